// Round 4
// baseline (66.868 us; speedup 1.0000x reference)
//
#include <hip/hip_runtime.h>
#include <math.h>

#define NNODE 2048
#define NEDGE 32768
#define DD 64
#define GG 16
#define NPG 128   // nodes per graph
#define PP 500    // kde grid points
#define QQ 20     // quantiles
#define CAP 64    // adjacency bucket capacity (max in-degree ~35 for this dataset)

__device__ __forceinline__ float fexp2(float x) { return __builtin_amdgcn_exp2f(x); }
__device__ __forceinline__ float frcp(float x)  { return __builtin_amdgcn_rcpf(x); }
__device__ __forceinline__ float frsq(float x)  { return __builtin_amdgcn_rsqf(x); }

struct __align__(8) f2 { float x, y; };

struct KdeS { f2 bc[NPG]; f2 cg[512]; float sred[8]; float wtot[8]; float kfv[QQ]; };
struct AttS { float sc[NPG]; float part[8][DD]; float pooled[DD]; };
struct XwS  { float Ws[DD][DD]; float xr[8][DD]; };
union SmemU { KdeS k; AttS a; XwS x; };

// ---------- zero the 2560-word scratch header (cnt[2048] + kout[512]) ----------
__global__ void k_zero(float* __restrict__ p) {
    p[blockIdx.x * 512 + threadIdx.x] = 0.f;
}

// ---------- CSR-bucket fill: counts + adjacency (keyed by dst, holds src) ----------
__global__ void k_fill(const int* __restrict__ ei, int* __restrict__ cnt,
                       int* __restrict__ csr) {
    int e = blockIdx.x * 256 + threadIdx.x;
    int s = ei[e], dstn = ei[NEDGE + e];
    int pos = atomicAdd(&cnt[dstn], 1);
    if (pos < CAP) csr[dstn * CAP + pos] = s;
}

// ---------- shared attention-pool device helper (512 threads) ----------
__device__ __forceinline__ void att_pool(AttS& s, const float* __restrict__ xg,
                                         const float* __restrict__ gW, float gb) {
    int t = threadIdx.x, lane = t & 63, wid = t >> 6;
    // gate scores: 4 threads per node
    int node = t >> 2, seg = t & 3;
    const float* row = xg + node * DD + seg * 16;
    const float* gw = gW + seg * 16;
    float v = 0.f;
    #pragma unroll
    for (int k = 0; k < 16; k++) v = fmaf(row[k], gw[k], v);
    v += __shfl_xor(v, 1);
    v += __shfl_xor(v, 2);
    if (seg == 0) s.sc[node] = v + gb;
    __syncthreads();
    // softmax over the 128 scores (wave 0)
    if (wid == 0) {
        float v0 = s.sc[lane], v1 = s.sc[lane + 64];
        float m = fmaxf(v0, v1);
        for (int o = 32; o; o >>= 1) m = fmaxf(m, __shfl_xor(m, o));
        float e0 = __expf(v0 - m), e1 = __expf(v1 - m);
        float ssum = e0 + e1;
        for (int o = 32; o; o >>= 1) ssum += __shfl_xor(ssum, o);
        float inv = frcp(ssum);
        s.sc[lane] = e0 * inv;
        s.sc[lane + 64] = e1 * inv;
    }
    __syncthreads();
    // weighted pool: (dim, chunk-of-16-nodes) per thread
    int d2 = t & 63, ch = t >> 6;
    const float* base = xg + ch * 16 * DD + d2;
    const float* av = s.sc + ch * 16;
    float p = 0.f;
    #pragma unroll
    for (int i = 0; i < 16; i++) p = fmaf(av[i], base[i * DD], p);
    s.part[ch][d2] = p;
    __syncthreads();
    if (t < DD) {
        float pd = 0.f;
        #pragma unroll
        for (int c2 = 0; c2 < 8; c2++) pd += s.part[c2][t];
        s.pooled[t] = pd;
    }
    __syncthreads();
}

// ---------- mega kernel: [0,1024) KDE | [1024,1040) att-pool | [1040,1296) xw ----------
__global__ __launch_bounds__(512) void k_mega(
    const float* __restrict__ xin, const int* __restrict__ cnt,
    float* __restrict__ xwout, float* __restrict__ hb, float* __restrict__ kout,
    const float* __restrict__ gcnW,
    const float* __restrict__ gateW, const float* __restrict__ gateB,
    const float* __restrict__ lpW, const float* __restrict__ lpB,
    const float* __restrict__ kpW) {
    __shared__ SmemU sm;
    int b = blockIdx.x, t = threadIdx.x, lane = t & 63, wid = t >> 6;

    if (b < GG * DD) {
        // ================= KDE role: one block per (g,d) =================
        int g = b >> 6, d = b & 63;
        const float* xg = xin + g * NPG * DD + d;
        float a = 0.f;
        if (t < NPG) a = xg[t * DD];
        if (wid < 2) {
            float mn = a, mx = a, smv = a;
            for (int o = 32; o; o >>= 1) {
                mn = fminf(mn, __shfl_xor(mn, o));
                mx = fmaxf(mx, __shfl_xor(mx, o));
                smv += __shfl_xor(smv, o);
            }
            if (lane == 0) {
                sm.k.sred[wid * 3 + 0] = mn;
                sm.k.sred[wid * 3 + 1] = mx;
                sm.k.sred[wid * 3 + 2] = smv;
            }
        }
        __syncthreads();
        float mn = fminf(sm.k.sred[0], sm.k.sred[3]) - 1e-6f;
        float mx = fmaxf(sm.k.sred[1], sm.k.sred[4]) + 1e-6f;
        float mean = (sm.k.sred[2] + sm.k.sred[5]) * (1.f / 128.f);
        if (wid < 2) {
            float dv = a - mean;
            float sq = dv * dv;
            for (int o = 32; o; o >>= 1) sq += __shfl_xor(sq, o);
            if (lane == 0) sm.k.sred[6 + wid] = sq;
        }
        __syncthreads();
        float var = fmaxf((sm.k.sred[6] + sm.k.sred[7]) * (1.f / 128.f), 0.f);
        float sd = sqrtf(var) + (1e-8f / 3.0f);
        float h = 0.4016648901252554f * sd;          // 1.06 * 128^-0.2 * std
        const float L2E = 1.4426950408889634f;
        float A = -0.5f * L2E * frcp(h * h);         // log2-space exponent coeff
        if (t < NPG) { f2 v; v.x = -2.f * A * a; v.y = A * a * a; sm.k.bc[t] = v; }
        __syncthreads();
        float step = (mx - mn) * (1.f / 499.f);
        float gp = fmaf(step, (float)t, mn);
        float gA = A * gp * gp;
        float ac0 = 0.f, ac1 = 0.f, ac2 = 0.f, ac3 = 0.f;
        #pragma unroll 8
        for (int j = 0; j < NPG; j += 4) {
            f2 b0 = sm.k.bc[j], b1 = sm.k.bc[j + 1], b2 = sm.k.bc[j + 2], b3 = sm.k.bc[j + 3];
            ac0 += fexp2(gA + fmaf(b0.x, gp, b0.y));
            ac1 += fexp2(gA + fmaf(b1.x, gp, b1.y));
            ac2 += fexp2(gA + fmaf(b2.x, gp, b2.y));
            ac3 += fexp2(gA + fmaf(b3.x, gp, b3.y));
        }
        float invnh = frcp(128.f * h * 2.5066282746310002f);  // 1/(n h sqrt(2pi))
        float dens = (t < PP) ? ((ac0 + ac1) + (ac2 + ac3)) * invnh : 0.f;
        // block-inclusive CDF scan
        float sc2 = dens;
        for (int o = 1; o < 64; o <<= 1) {
            float u = __shfl_up(sc2, o);
            if (lane >= o) sc2 += u;
        }
        if (lane == 63) sm.k.wtot[wid] = sc2;
        __syncthreads();
        float offs = 0.f, total = 0.f;
        #pragma unroll
        for (int w = 0; w < 8; w++) {
            float wv = sm.k.wtot[w];
            if (w < wid) offs += wv;
            total += wv;
        }
        float c = (offs + sc2) * frcp(fmaxf(total, 1e-8f));
        f2 cgv; cgv.x = (t < PP) ? c : 4.0f; cgv.y = (t < PP) ? gp : 0.f;
        sm.k.cg[t] = cgv;
        __syncthreads();
        // transposed quantile phase: 16-lane group per quantile
        int grp = t >> 4, sub = t & 15;
        if (grp < QQ) {
            float qv = (float)grp * (1.f / 19.f);
            float sw0 = 0.f, sw1 = 0.f, sg0 = 0.f, sg1 = 0.f;
            #pragma unroll
            for (int i = 0; i < 32; i += 2) {
                f2 v0 = sm.k.cg[i * 16 + sub];
                f2 v1 = sm.k.cg[(i + 1) * 16 + sub];
                float e0 = fexp2(fabsf(v0.x - qv) * 144.26950408889634f);  // 100*log2(e)
                float e1 = fexp2(fabsf(v1.x - qv) * 144.26950408889634f);
                float w0 = frcp(1.f + e0), w1 = frcp(1.f + e1);
                sw0 += w0; sg0 = fmaf(w0, v0.y, sg0);
                sw1 += w1; sg1 = fmaf(w1, v1.y, sg1);
            }
            float sw = sw0 + sw1, sg = sg0 + sg1;
            #pragma unroll
            for (int o = 1; o < 16; o <<= 1) {
                sw += __shfl_xor(sw, o);
                sg += __shfl_xor(sg, o);
            }
            if (sub == 0) sm.k.kfv[grp] = sg * frcp(sw + 1e-8f);
        }
        __syncthreads();
        // fused KDE-head partial: kf(d,:) @ kpW rows -> 16 atomics
        if (t < 16) {
            float v = 0.f;
            #pragma unroll
            for (int q = 0; q < QQ; q++) v = fmaf(sm.k.kfv[q], kpW[(d * QQ + q) * 16 + t], v);
            atomicAdd(&kout[g * 16 + t], v);
        }
    } else if (b < GG * DD + GG) {
        // ================= attention-pool + linear head =================
        int g = b - GG * DD;
        att_pool(sm.a, xin + g * NPG * DD, gateW, gateB[0]);
        if (t < 16) {
            float o = lpB[t];
            #pragma unroll
            for (int d2 = 0; d2 < DD; d2++) o = fmaf(sm.a.pooled[d2], lpW[d2 * 16 + t], o);
            hb[g * 16 + t] = o;
        }
    } else {
        // ================= xw' = (x @ W) * dinv[row]: 8 rows per block =================
        int rb = b - (GG * DD + GG);
        int r0 = rb * 8;
        for (int i = t; i < DD * DD; i += 512) sm.x.Ws[i >> 6][i & 63] = gcnW[i];
        sm.x.xr[wid][lane] = xin[(r0 + wid) * DD + lane];
        __syncthreads();
        float s = 0.f;
        #pragma unroll
        for (int k = 0; k < DD; k++) s = fmaf(sm.x.xr[wid][k], sm.x.Ws[k][lane], s);
        float di = frsq((float)cnt[r0 + wid] + 1.0f);
        xwout[(r0 + wid) * DD + lane] = s * di;
    }
}

// ---------- gather: cur[n] = dinv[n]*(sum_src xw'[src] + xw'[n]) + b ----------
__global__ __launch_bounds__(512) void k_gather(const int* __restrict__ cnt,
                                                const int* __restrict__ csr,
                                                const float* __restrict__ xw,
                                                const float* __restrict__ bvec,
                                                float* __restrict__ cur) {
    int t = threadIdx.x, lane = t & 63, wid = t >> 6;
    int n = blockIdx.x * 8 + wid;
    int ec = cnt[n];
    if (ec > CAP) ec = CAP;
    const int* lst = csr + n * CAP;
    float sum = 0.f;
    int j = 0;
    for (; j + 4 <= ec; j += 4) {
        int s0 = lst[j], s1 = lst[j + 1], s2 = lst[j + 2], s3 = lst[j + 3];
        sum += xw[s0 * DD + lane] + xw[s1 * DD + lane] + xw[s2 * DD + lane] + xw[s3 * DD + lane];
    }
    for (; j < ec; j++) sum += xw[lst[j] * DD + lane];
    float di = frsq((float)cnt[n] + 1.f);
    cur[n * DD + lane] = di * (sum + xw[n * DD + lane]) + bvec[lane];
}

// ---------- final: att-pool(cur2) + cls head + combine -> out[g] ----------
__global__ __launch_bounds__(512) void k_fin(const float* __restrict__ cur2,
    const float* __restrict__ gW2, const float* __restrict__ gb2,
    const float* __restrict__ clsW, const float* __restrict__ clsB,
    const float* __restrict__ hb, const float* __restrict__ kout,
    const float* __restrict__ kpb0, const float* __restrict__ kpb1,
    const float* __restrict__ beta, const float* __restrict__ h0s,
    float* __restrict__ out) {
    __shared__ SmemU sm;
    __shared__ float red[16];
    int g = blockIdx.x, t = threadIdx.x;
    att_pool(sm.a, cur2 + g * NPG * DD, gW2, gb2[0]);
    if (t < 16) {
        float h2 = clsB[t];
        #pragma unroll
        for (int d2 = 0; d2 < DD; d2++) h2 = fmaf(sm.a.pooled[d2], clsW[d2 * 16 + t], h2);
        float mo = (hb[g * 16 + t] + hb[256 + g * 16 + t] + h2) * (1.f / 3.f);
        float ko = (kout[g * 16 + t] + kpb0[t] + kout[256 + g * 16 + t] + kpb1[t]) * 0.5f;
        red[t] = (mo + ko) * beta[t];
    }
    __syncthreads();
    if (t == 0) {
        float s = 0.f;
        #pragma unroll
        for (int j = 0; j < 16; j++) s += red[j];
        out[g] = s + h0s[0];
    }
}

extern "C" void kernel_launch(void* const* d_in, const int* in_sizes, int n_in,
                              void* d_out, int out_size, void* d_ws, size_t ws_size,
                              hipStream_t stream) {
    const float* x       = (const float*)d_in[0];
    const int*   ei      = (const int*)  d_in[1];
    const float* gcn_W0  = (const float*)d_in[2];
    const float* gcn_b0  = (const float*)d_in[3];
    const float* gcn_W1  = (const float*)d_in[4];
    const float* gcn_b1  = (const float*)d_in[5];
    const float* lp_W0   = (const float*)d_in[6];
    const float* lp_b0   = (const float*)d_in[7];
    const float* lp_W1   = (const float*)d_in[8];
    const float* lp_b1   = (const float*)d_in[9];
    const float* cls_W   = (const float*)d_in[10];
    const float* cls_b   = (const float*)d_in[11];
    const float* kp_W0   = (const float*)d_in[12];
    const float* kp_b0   = (const float*)d_in[13];
    const float* kp_W1   = (const float*)d_in[14];
    const float* kp_b1   = (const float*)d_in[15];
    const float* gate_W0 = (const float*)d_in[16];
    const float* gate_b0 = (const float*)d_in[17];
    const float* gate_W1 = (const float*)d_in[18];
    const float* gate_b1 = (const float*)d_in[19];
    const float* gate_W2 = (const float*)d_in[20];
    const float* gate_b2 = (const float*)d_in[21];
    const float* beta    = (const float*)d_in[22];
    const float* h0s     = (const float*)d_in[23];

    float* ws  = (float*)d_ws;
    int* cnt   = (int*)ws;                         // [2048]
    float* kout = ws + 2048;                       // [512]  (L0: +0, L1: +256)
    int* csr   = (int*)(ws + 2560);                // [2048*64]
    float* A   = ws + 2560 + NNODE * CAP;          // xw' [131072]
    float* B   = A + NNODE * DD;                   // cur  [131072]
    float* hb  = B + NNODE * DD;                   // [512] (h0: +0, h1: +256)

    // zero cnt + kout (contiguous 2560 elements) — our own kernel, NOT
    // hipMemsetAsync: the runtime's fillBufferAligned blit costs ~40us/replay.
    k_zero<<<5, 512, 0, stream>>>(ws);

    k_fill<<<NEDGE / 256, 256, 0, stream>>>(ei, cnt, csr);

    // layer 0
    k_mega<<<GG * DD + GG + NNODE / 8, 512, 0, stream>>>(
        x, cnt, A, hb, kout, gcn_W0, gate_W0, gate_b0, lp_W0, lp_b0, kp_W0);
    k_gather<<<NNODE / 8, 512, 0, stream>>>(cnt, csr, A, gcn_b0, B);

    // layer 1
    k_mega<<<GG * DD + GG + NNODE / 8, 512, 0, stream>>>(
        B, cnt, A, hb + 256, kout + 256, gcn_W1, gate_W1, gate_b1, lp_W1, lp_b1, kp_W1);
    k_gather<<<NNODE / 8, 512, 0, stream>>>(cnt, csr, A, gcn_b1, B);

    // final pool + combine
    k_fin<<<GG, 512, 0, stream>>>(B, gate_W2, gate_b2, cls_W, cls_b,
                                  hb, kout, kp_b0, kp_b1, beta, h0s, (float*)d_out);
}

// Round 5
// 66.451 us; speedup vs baseline: 1.0063x; 1.0063x over previous
//
#include <hip/hip_runtime.h>
#include <math.h>

#define NNODE 2048
#define NEDGE 32768
#define DD 64
#define GG 16
#define NPG 128   // nodes per graph
#define PP 500    // kde grid points
#define QQ 20     // quantiles
#define CAP 64    // adjacency bucket capacity (max in-degree ~35 for this dataset)

__device__ __forceinline__ float fexp2(float x) { return __builtin_amdgcn_exp2f(x); }
__device__ __forceinline__ float frcp(float x)  { return __builtin_amdgcn_rcpf(x); }
__device__ __forceinline__ float frsq(float x)  { return __builtin_amdgcn_rsqf(x); }

struct __align__(8) f2 { float x, y; };

struct KdeS { f2 bc[NPG]; f2 cg[512]; float sred[8]; float wtot[8]; float kfv[QQ]; };
struct AttS { float sc[NPG]; float part[8][DD]; float pooled[DD]; };
struct XwS  { float Ws[DD][DD]; float xr[8][DD]; };
union SmemU { KdeS k; AttS a; XwS x; };

// ---------- zero cnt[2048] ints (only buffer needing per-replay zeroing) ----------
__global__ void k_zero(int* __restrict__ p) {
    p[blockIdx.x * 512 + threadIdx.x] = 0;
}

// ---------- CSR-bucket fill: counts + adjacency (keyed by dst, holds src) ----------
__global__ void k_fill(const int* __restrict__ ei, int* __restrict__ cnt,
                       int* __restrict__ csr) {
    int e = blockIdx.x * 256 + threadIdx.x;
    int s = ei[e], dstn = ei[NEDGE + e];
    int pos = atomicAdd(&cnt[dstn], 1);
    if (pos < CAP) csr[dstn * CAP + pos] = s;
}

// ---------- shared attention-pool device helper (512 threads) ----------
__device__ __forceinline__ void att_pool(AttS& s, const float* __restrict__ xg,
                                         const float* __restrict__ gW, float gb) {
    int t = threadIdx.x, lane = t & 63, wid = t >> 6;
    // gate scores: 4 threads per node
    int node = t >> 2, seg = t & 3;
    const float* row = xg + node * DD + seg * 16;
    const float* gw = gW + seg * 16;
    float v = 0.f;
    #pragma unroll
    for (int k = 0; k < 16; k++) v = fmaf(row[k], gw[k], v);
    v += __shfl_xor(v, 1);
    v += __shfl_xor(v, 2);
    if (seg == 0) s.sc[node] = v + gb;
    __syncthreads();
    // softmax over the 128 scores (wave 0)
    if (wid == 0) {
        float v0 = s.sc[lane], v1 = s.sc[lane + 64];
        float m = fmaxf(v0, v1);
        for (int o = 32; o; o >>= 1) m = fmaxf(m, __shfl_xor(m, o));
        float e0 = __expf(v0 - m), e1 = __expf(v1 - m);
        float ssum = e0 + e1;
        for (int o = 32; o; o >>= 1) ssum += __shfl_xor(ssum, o);
        float inv = frcp(ssum);
        s.sc[lane] = e0 * inv;
        s.sc[lane + 64] = e1 * inv;
    }
    __syncthreads();
    // weighted pool: (dim, chunk-of-16-nodes) per thread
    int d2 = t & 63, ch = t >> 6;
    const float* base = xg + ch * 16 * DD + d2;
    const float* av = s.sc + ch * 16;
    float p = 0.f;
    #pragma unroll
    for (int i = 0; i < 16; i++) p = fmaf(av[i], base[i * DD], p);
    s.part[ch][d2] = p;
    __syncthreads();
    if (t < DD) {
        float pd = 0.f;
        #pragma unroll
        for (int c2 = 0; c2 < 8; c2++) pd += s.part[c2][t];
        s.pooled[t] = pd;
    }
    __syncthreads();
}

// ---------- mega kernel: [0,1024) KDE | [1024,1040) att-pool | [1040,1296) xw ----------
__global__ __launch_bounds__(512) void k_mega(
    const float* __restrict__ xin, const int* __restrict__ cnt,
    float* __restrict__ xwout, float* __restrict__ hb, float* __restrict__ kpart,
    const float* __restrict__ gcnW,
    const float* __restrict__ gateW, const float* __restrict__ gateB,
    const float* __restrict__ lpW, const float* __restrict__ lpB,
    const float* __restrict__ kpW) {
    __shared__ SmemU sm;
    int b = blockIdx.x, t = threadIdx.x, lane = t & 63, wid = t >> 6;

    if (b < GG * DD) {
        // ================= KDE role: one block per (g,d) =================
        int g = b >> 6, d = b & 63;
        const float* xg = xin + g * NPG * DD + d;
        float a = 0.f;
        if (t < NPG) a = xg[t * DD];
        if (wid < 2) {
            float mn = a, mx = a, smv = a;
            for (int o = 32; o; o >>= 1) {
                mn = fminf(mn, __shfl_xor(mn, o));
                mx = fmaxf(mx, __shfl_xor(mx, o));
                smv += __shfl_xor(smv, o);
            }
            if (lane == 0) {
                sm.k.sred[wid * 3 + 0] = mn;
                sm.k.sred[wid * 3 + 1] = mx;
                sm.k.sred[wid * 3 + 2] = smv;
            }
        }
        __syncthreads();
        float mn = fminf(sm.k.sred[0], sm.k.sred[3]) - 1e-6f;
        float mx = fmaxf(sm.k.sred[1], sm.k.sred[4]) + 1e-6f;
        float mean = (sm.k.sred[2] + sm.k.sred[5]) * (1.f / 128.f);
        if (wid < 2) {
            float dv = a - mean;
            float sq = dv * dv;
            for (int o = 32; o; o >>= 1) sq += __shfl_xor(sq, o);
            if (lane == 0) sm.k.sred[6 + wid] = sq;
        }
        __syncthreads();
        float var = fmaxf((sm.k.sred[6] + sm.k.sred[7]) * (1.f / 128.f), 0.f);
        float sd = sqrtf(var) + (1e-8f / 3.0f);
        float h = 0.4016648901252554f * sd;          // 1.06 * 128^-0.2 * std
        const float L2E = 1.4426950408889634f;
        float A = -0.5f * L2E * frcp(h * h);         // log2-space exponent coeff
        if (t < NPG) { f2 v; v.x = -2.f * A * a; v.y = A * a * a; sm.k.bc[t] = v; }
        __syncthreads();
        float step = (mx - mn) * (1.f / 499.f);
        float gp = fmaf(step, (float)t, mn);
        float gA = A * gp * gp;
        // density loop: b128 LDS reads (2 nodes' (B,C) per float4), 4 exp chains
        const float4* bc4 = (const float4*)sm.k.bc;
        float ac0 = 0.f, ac1 = 0.f, ac2 = 0.f, ac3 = 0.f;
        #pragma unroll 4
        for (int j4 = 0; j4 < 64; j4 += 2) {
            float4 p = bc4[j4], q = bc4[j4 + 1];
            ac0 += fexp2(gA + fmaf(p.x, gp, p.y));
            ac1 += fexp2(gA + fmaf(p.z, gp, p.w));
            ac2 += fexp2(gA + fmaf(q.x, gp, q.y));
            ac3 += fexp2(gA + fmaf(q.z, gp, q.w));
        }
        float invnh = frcp(128.f * h * 2.5066282746310002f);  // 1/(n h sqrt(2pi))
        float dens = (t < PP) ? ((ac0 + ac1) + (ac2 + ac3)) * invnh : 0.f;
        // block-inclusive CDF scan
        float sc2 = dens;
        for (int o = 1; o < 64; o <<= 1) {
            float u = __shfl_up(sc2, o);
            if (lane >= o) sc2 += u;
        }
        if (lane == 63) sm.k.wtot[wid] = sc2;
        __syncthreads();
        float offs = 0.f, total = 0.f;
        #pragma unroll
        for (int w = 0; w < 8; w++) {
            float wv = sm.k.wtot[w];
            if (w < wid) offs += wv;
            total += wv;
        }
        float c = (offs + sc2) * frcp(fmaxf(total, 1e-8f));
        f2 cgv; cgv.x = (t < PP) ? c : 4.0f; cgv.y = (t < PP) ? gp : 0.f;
        sm.k.cg[t] = cgv;
        __syncthreads();
        // transposed quantile phase: 16-lane group per quantile
        int grp = t >> 4, sub = t & 15;
        if (grp < QQ) {
            float qv = (float)grp * (1.f / 19.f);
            float sw0 = 0.f, sw1 = 0.f, sg0 = 0.f, sg1 = 0.f;
            #pragma unroll
            for (int i = 0; i < 32; i += 2) {
                f2 v0 = sm.k.cg[i * 16 + sub];
                f2 v1 = sm.k.cg[(i + 1) * 16 + sub];
                float e0 = fexp2(fabsf(v0.x - qv) * 144.26950408889634f);  // 100*log2(e)
                float e1 = fexp2(fabsf(v1.x - qv) * 144.26950408889634f);
                float w0 = frcp(1.f + e0), w1 = frcp(1.f + e1);
                sw0 += w0; sg0 = fmaf(w0, v0.y, sg0);
                sw1 += w1; sg1 = fmaf(w1, v1.y, sg1);
            }
            float sw = sw0 + sw1, sg = sg0 + sg1;
            #pragma unroll
            for (int o = 1; o < 16; o <<= 1) {
                sw += __shfl_xor(sw, o);
                sg += __shfl_xor(sg, o);
            }
            if (sub == 0) sm.k.kfv[grp] = sg * frcp(sw + 1e-8f);
        }
        __syncthreads();
        // fused KDE-head partial: kf(d,:) @ kpW rows -> per-block slot (no atomics)
        if (t < 16) {
            float v = 0.f;
            #pragma unroll
            for (int q = 0; q < QQ; q++) v = fmaf(sm.k.kfv[q], kpW[(d * QQ + q) * 16 + t], v);
            kpart[b * 16 + t] = v;
        }
    } else if (b < GG * DD + GG) {
        // ================= attention-pool + linear head =================
        int g = b - GG * DD;
        att_pool(sm.a, xin + g * NPG * DD, gateW, gateB[0]);
        if (t < 16) {
            float o = lpB[t];
            #pragma unroll
            for (int d2 = 0; d2 < DD; d2++) o = fmaf(sm.a.pooled[d2], lpW[d2 * 16 + t], o);
            hb[g * 16 + t] = o;
        }
    } else {
        // ================= xw' = (x @ W) * dinv[row]: 8 rows per block =================
        int rb = b - (GG * DD + GG);
        int r0 = rb * 8;
        float4* Wv = (float4*)&sm.x.Ws[0][0];
        const float4* Gv = (const float4*)gcnW;
        Wv[t] = Gv[t];
        Wv[t + 512] = Gv[t + 512];
        sm.x.xr[wid][lane] = xin[(r0 + wid) * DD + lane];
        __syncthreads();
        float s = 0.f;
        #pragma unroll
        for (int k = 0; k < DD; k++) s = fmaf(sm.x.xr[wid][k], sm.x.Ws[k][lane], s);
        float di = frsq((float)cnt[r0 + wid] + 1.0f);
        xwout[(r0 + wid) * DD + lane] = s * di;
    }
}

// ---------- gather: cur[n] = dinv[n]*(sum_src xw'[src] + xw'[n]) + b ----------
__global__ __launch_bounds__(512) void k_gather(const int* __restrict__ cnt,
                                                const int* __restrict__ csr,
                                                const float* __restrict__ xw,
                                                const float* __restrict__ bvec,
                                                float* __restrict__ cur) {
    int t = threadIdx.x, lane = t & 63, wid = t >> 6;
    int n = blockIdx.x * 8 + wid;
    int ec = cnt[n];
    if (ec > CAP) ec = CAP;
    const int* lst = csr + n * CAP;
    float sum0 = 0.f, sum1 = 0.f;
    int j = 0;
    for (; j + 4 <= ec; j += 4) {
        int s0 = lst[j], s1 = lst[j + 1], s2 = lst[j + 2], s3 = lst[j + 3];
        sum0 += xw[s0 * DD + lane] + xw[s1 * DD + lane];
        sum1 += xw[s2 * DD + lane] + xw[s3 * DD + lane];
    }
    for (; j < ec; j++) sum0 += xw[lst[j] * DD + lane];
    float di = frsq((float)cnt[n] + 1.f);
    cur[n * DD + lane] = di * ((sum0 + sum1) + xw[n * DD + lane]) + bvec[lane];
}

// ---------- final: att-pool(cur2) + cls head + kpart reduction + combine ----------
__global__ __launch_bounds__(512) void k_fin(const float* __restrict__ cur2,
    const float* __restrict__ gW2, const float* __restrict__ gb2,
    const float* __restrict__ clsW, const float* __restrict__ clsB,
    const float* __restrict__ hb, const float* __restrict__ kpart,
    const float* __restrict__ kpb0, const float* __restrict__ kpb1,
    const float* __restrict__ beta, const float* __restrict__ h0s,
    float* __restrict__ out) {
    __shared__ SmemU sm;
    __shared__ float red[16];
    int g = blockIdx.x, t = threadIdx.x;
    att_pool(sm.a, cur2 + g * NPG * DD, gW2, gb2[0]);
    if (t < 16) {
        float h2 = clsB[t];
        #pragma unroll
        for (int d2 = 0; d2 < DD; d2++) h2 = fmaf(sm.a.pooled[d2], clsW[d2 * 16 + t], h2);
        // sum the 64 per-dim KDE-head partials for each layer
        const float* kp0 = kpart + g * DD * 16 + t;
        const float* kp1 = kp0 + GG * DD * 16;
        float s0 = 0.f, s1 = 0.f;
        #pragma unroll
        for (int d2 = 0; d2 < DD; d2++) {
            s0 += kp0[d2 * 16];
            s1 += kp1[d2 * 16];
        }
        float mo = (hb[g * 16 + t] + hb[256 + g * 16 + t] + h2) * (1.f / 3.f);
        float ko = (s0 + kpb0[t] + s1 + kpb1[t]) * 0.5f;
        red[t] = (mo + ko) * beta[t];
    }
    __syncthreads();
    if (t == 0) {
        float s = 0.f;
        #pragma unroll
        for (int j = 0; j < 16; j++) s += red[j];
        out[g] = s + h0s[0];
    }
}

extern "C" void kernel_launch(void* const* d_in, const int* in_sizes, int n_in,
                              void* d_out, int out_size, void* d_ws, size_t ws_size,
                              hipStream_t stream) {
    const float* x       = (const float*)d_in[0];
    const int*   ei      = (const int*)  d_in[1];
    const float* gcn_W0  = (const float*)d_in[2];
    const float* gcn_b0  = (const float*)d_in[3];
    const float* gcn_W1  = (const float*)d_in[4];
    const float* gcn_b1  = (const float*)d_in[5];
    const float* lp_W0   = (const float*)d_in[6];
    const float* lp_b0   = (const float*)d_in[7];
    const float* lp_W1   = (const float*)d_in[8];
    const float* lp_b1   = (const float*)d_in[9];
    const float* cls_W   = (const float*)d_in[10];
    const float* cls_b   = (const float*)d_in[11];
    const float* kp_W0   = (const float*)d_in[12];
    const float* kp_b0   = (const float*)d_in[13];
    const float* kp_W1   = (const float*)d_in[14];
    const float* kp_b1   = (const float*)d_in[15];
    const float* gate_W0 = (const float*)d_in[16];
    const float* gate_b0 = (const float*)d_in[17];
    const float* gate_W1 = (const float*)d_in[18];
    const float* gate_b1 = (const float*)d_in[19];
    const float* gate_W2 = (const float*)d_in[20];
    const float* gate_b2 = (const float*)d_in[21];
    const float* beta    = (const float*)d_in[22];
    const float* h0s     = (const float*)d_in[23];

    float* ws  = (float*)d_ws;
    int* cnt   = (int*)ws;                         // [2048] (zeroed per replay)
    int* csr   = (int*)(ws + 2048);                // [2048*64]
    float* A   = ws + 2048 + NNODE * CAP;          // xw' [131072]
    float* B   = A + NNODE * DD;                   // cur  [131072]
    float* hb  = B + NNODE * DD;                   // [512] (h0: +0, h1: +256)
    float* kp  = hb + 512;                         // kpart [2][1024*16]

    // zero cnt (8 KB) — own kernel; hipMemsetAsync's blit costs ~40us/replay.
    k_zero<<<4, 512, 0, stream>>>(cnt);

    k_fill<<<NEDGE / 256, 256, 0, stream>>>(ei, cnt, csr);

    // layer 0
    k_mega<<<GG * DD + GG + NNODE / 8, 512, 0, stream>>>(
        x, cnt, A, hb, kp, gcn_W0, gate_W0, gate_b0, lp_W0, lp_b0, kp_W0);
    k_gather<<<NNODE / 8, 512, 0, stream>>>(cnt, csr, A, gcn_b0, B);

    // layer 1
    k_mega<<<GG * DD + GG + NNODE / 8, 512, 0, stream>>>(
        B, cnt, A, hb + 256, kp + GG * DD * 16, gcn_W1, gate_W1, gate_b1, lp_W1, lp_b1, kp_W1);
    k_gather<<<NNODE / 8, 512, 0, stream>>>(cnt, csr, A, gcn_b1, B);

    // final pool + combine
    k_fin<<<GG, 512, 0, stream>>>(B, gate_W2, gate_b2, cls_W, cls_b,
                                  hb, kp, kp_b0, kp_b1, beta, h0s, (float*)d_out);
}